// Round 1
// baseline (703.102 us; speedup 1.0000x reference)
//
#include <hip/hip_runtime.h>

#define D 128

// ---------------- degree / init ----------------
__global__ void k_init(int* __restrict__ degi, int* __restrict__ fill_ctr, int n) {
    int i = blockIdx.x * blockDim.x + threadIdx.x;
    if (i < n) { degi[i] = 1; fill_ctr[i] = 0; }   // deg starts at 1 (self-loop)
}

__global__ void k_count(const int* __restrict__ dst, int* __restrict__ degi, int E) {
    int e = blockIdx.x * blockDim.x + threadIdx.x;
    if (e < E) atomicAdd(&degi[dst[e]], 1);
}

__global__ void k_dinv(const int* __restrict__ degi, float* __restrict__ dinv, int n) {
    int i = blockIdx.x * blockDim.x + threadIdx.x;
    if (i < n) dinv[i] = rsqrtf((float)degi[i]);   // deg >= 1 always (self-loop)
}

// ---------------- exclusive scan of edge counts (degi[i]-1) over n+1 elems ----------------
#define SCAN_BS 256
#define SCAN_ITEMS 4
#define SCAN_CHUNK (SCAN_BS * SCAN_ITEMS)

__device__ inline int count_at(const int* degi, int i, int n) {
    return (i < n) ? (degi[i] - 1) : 0;
}

__global__ void k_scan_partial(const int* __restrict__ degi, int* __restrict__ blockSums,
                               int n, int total) {
    __shared__ int s[SCAN_BS];
    int t = threadIdx.x;
    int base = blockIdx.x * SCAN_CHUNK + t * SCAN_ITEMS;
    int sum = 0;
    for (int j = 0; j < SCAN_ITEMS; j++) {
        int idx = base + j;
        if (idx < total) sum += count_at(degi, idx, n);
    }
    s[t] = sum; __syncthreads();
    for (int off = 1; off < SCAN_BS; off <<= 1) {
        int v = (t >= off) ? s[t - off] : 0;
        __syncthreads();
        s[t] += v;
        __syncthreads();
    }
    if (t == SCAN_BS - 1) blockSums[blockIdx.x] = s[t];
}

__global__ void k_scan_sums(int* __restrict__ blockSums, int nb) {
    __shared__ int s[1024];
    int t = threadIdx.x;
    int mine = (t < nb) ? blockSums[t] : 0;
    s[t] = mine; __syncthreads();
    for (int off = 1; off < 1024; off <<= 1) {
        int v = (t >= off) ? s[t - off] : 0;
        __syncthreads();
        s[t] += v;
        __syncthreads();
    }
    if (t < nb) blockSums[t] = s[t] - mine;   // exclusive
}

__global__ void k_scan_write(const int* __restrict__ degi, const int* __restrict__ blockSums,
                             int* __restrict__ row_ptr, int n, int total) {
    __shared__ int s[SCAN_BS];
    int t = threadIdx.x;
    int base = blockIdx.x * SCAN_CHUNK + t * SCAN_ITEMS;
    int c[SCAN_ITEMS];
    int sum = 0;
    for (int j = 0; j < SCAN_ITEMS; j++) {
        int idx = base + j;
        c[j] = (idx < total) ? count_at(degi, idx, n) : 0;
        sum += c[j];
    }
    int mine = sum;
    s[t] = sum; __syncthreads();
    for (int off = 1; off < SCAN_BS; off <<= 1) {
        int v = (t >= off) ? s[t - off] : 0;
        __syncthreads();
        s[t] += v;
        __syncthreads();
    }
    int off0 = blockSums[blockIdx.x] + (s[t] - mine);
    for (int j = 0; j < SCAN_ITEMS; j++) {
        int idx = base + j;
        if (idx < total) row_ptr[idx] = off0;
        off0 += c[j];
    }
}

__global__ void k_fill(const int* __restrict__ src, const int* __restrict__ dst,
                       const int* __restrict__ row_ptr, int* __restrict__ fill_ctr,
                       int* __restrict__ col, int E) {
    int e = blockIdx.x * blockDim.x + threadIdx.x;
    if (e < E) {
        int d = dst[e];
        int pos = row_ptr[d] + atomicAdd(&fill_ctr[d], 1);
        col[pos] = src[e];
    }
}

// ---------------- fp32 SGEMM: Y[M,128] = X[M,128] @ W[128,128] ----------------
// 128x128 block tile, 16x16 threads, 8x8 per-thread register tile, K-chunks of 32.
__global__ __launch_bounds__(256) void k_gemm(const float* __restrict__ X,
                                              const float* __restrict__ W,
                                              float* __restrict__ Y, int M) {
    __shared__ float XsT[32][132];   // transposed X tile, padded (stride 132 breaks conflicts)
    __shared__ float Ws[32][128];
    int t = threadIdx.x;
    int tx = t & 15, ty = t >> 4;
    int block_row = blockIdx.x * 128;
    float acc[8][8];
#pragma unroll
    for (int i = 0; i < 8; i++)
#pragma unroll
        for (int j = 0; j < 8; j++) acc[i][j] = 0.f;

    for (int kc = 0; kc < 128; kc += 32) {
#pragma unroll
        for (int i = 0; i < 4; i++) {            // stage X chunk (transposed)
            int idx = t + i * 256;               // 0..1023 float4 slots
            int r = idx >> 3;                    // 0..127 row in tile
            int kk = (idx & 7) << 2;             // 0..28 k offset
            int gr = block_row + r;
            float4 v = make_float4(0.f, 0.f, 0.f, 0.f);
            if (gr < M) v = *(const float4*)(X + (size_t)gr * D + kc + kk);
            XsT[kk + 0][r] = v.x; XsT[kk + 1][r] = v.y;
            XsT[kk + 2][r] = v.z; XsT[kk + 3][r] = v.w;
        }
#pragma unroll
        for (int i = 0; i < 4; i++) {            // stage W chunk (natural layout)
            int idx = t + i * 256;
            int k = idx >> 5;                    // 0..31
            int c = (idx & 31) << 2;             // 0..124
            *(float4*)&Ws[k][c] = *(const float4*)(W + (size_t)(kc + k) * D + c);
        }
        __syncthreads();
#pragma unroll
        for (int k = 0; k < 32; k++) {
            float a[8], b[8];
            *(float4*)&a[0] = *(const float4*)&XsT[k][ty * 8];
            *(float4*)&a[4] = *(const float4*)&XsT[k][ty * 8 + 4];
            *(float4*)&b[0] = *(const float4*)&Ws[k][tx * 8];
            *(float4*)&b[4] = *(const float4*)&Ws[k][tx * 8 + 4];
#pragma unroll
            for (int i = 0; i < 8; i++)
#pragma unroll
                for (int j = 0; j < 8; j++)
                    acc[i][j] = fmaf(a[i], b[j], acc[i][j]);
        }
        __syncthreads();
    }
#pragma unroll
    for (int i = 0; i < 8; i++) {
        int gr = block_row + ty * 8 + i;
        if (gr < M) {
            float4 o0 = make_float4(acc[i][0], acc[i][1], acc[i][2], acc[i][3]);
            float4 o1 = make_float4(acc[i][4], acc[i][5], acc[i][6], acc[i][7]);
            *(float4*)(Y + (size_t)gr * D + tx * 8) = o0;
            *(float4*)(Y + (size_t)gr * D + tx * 8 + 4) = o1;
        }
    }
}

// ---------------- pull aggregation: Y[i] = sum_{e in row i} dinv_s*dinv_i*H[s] + dinv_i^2*H[i] + b ----------------
// one wave per node; lane owns 2 columns (float2) -> 512B per gathered row, one txn.
__global__ __launch_bounds__(256) void k_agg(const float* __restrict__ H,
                                             const int* __restrict__ row_ptr,
                                             const int* __restrict__ col,
                                             const float* __restrict__ dinv,
                                             const float* __restrict__ bias,
                                             float* __restrict__ Y, int n, int do_relu) {
    int node = blockIdx.x * 4 + (threadIdx.x >> 6);
    int lane = threadIdx.x & 63;
    if (node >= n) return;
    float di = dinv[node];
    int start = row_ptr[node];
    int end = row_ptr[node + 1];

    const float2* Hi = (const float2*)(H + (size_t)node * D);
    float2 hs = Hi[lane];
    float2 acc;
    acc.x = di * di * hs.x;
    acc.y = di * di * hs.y;

    for (int e = start; e < end; e++) {
        int s = col[e];
        float w = di * dinv[s];
        float2 hv = ((const float2*)(H + (size_t)s * D))[lane];
        acc.x = fmaf(w, hv.x, acc.x);
        acc.y = fmaf(w, hv.y, acc.y);
    }
    float2 bb = ((const float2*)bias)[lane];
    acc.x += bb.x;
    acc.y += bb.y;
    if (do_relu) { acc.x = fmaxf(acc.x, 0.f); acc.y = fmaxf(acc.y, 0.f); }
    ((float2*)(Y + (size_t)node * D))[lane] = acc;
}

// ---------------- host ----------------
extern "C" void kernel_launch(void* const* d_in, const int* in_sizes, int n_in,
                              void* d_out, int out_size, void* d_ws, size_t ws_size,
                              hipStream_t stream) {
    const float* x  = (const float*)d_in[0];
    const int*   ei = (const int*)d_in[1];
    const float* W1 = (const float*)d_in[2];
    const float* b1 = (const float*)d_in[3];
    const float* W2 = (const float*)d_in[4];
    const float* b2 = (const float*)d_in[5];
    float* out = (float*)d_out;

    int n = in_sizes[0] / D;       // 100000
    int E = in_sizes[1] / 2;       // 1600000
    const int* src = ei;
    const int* dst = ei + E;

    char* p = (char*)d_ws;
    float* h_buf  = (float*)p;  p += (size_t)n * D * sizeof(float);
    float* y_buf  = (float*)p;  p += (size_t)n * D * sizeof(float);
    int*   degi   = (int*)p;    p += (size_t)n * sizeof(int);
    float* dinv   = (float*)p;  p += (size_t)n * sizeof(float);
    int*   row_ptr= (int*)p;    p += (size_t)(n + 1) * sizeof(int);
    int*   fill_c = (int*)p;    p += (size_t)n * sizeof(int);
    int*   bsums  = (int*)p;    p += 1024 * sizeof(int);
    int*   col    = (int*)p;    p += (size_t)E * sizeof(int);

    int total = n + 1;
    int nb = (total + SCAN_CHUNK - 1) / SCAN_CHUNK;   // 98 for n=100000, fits 1024-thread scan

    k_init<<<(n + 255) / 256, 256, 0, stream>>>(degi, fill_c, n);
    k_count<<<(E + 255) / 256, 256, 0, stream>>>(dst, degi, E);
    k_dinv<<<(n + 255) / 256, 256, 0, stream>>>(degi, dinv, n);
    k_scan_partial<<<nb, SCAN_BS, 0, stream>>>(degi, bsums, n, total);
    k_scan_sums<<<1, 1024, 0, stream>>>(bsums, nb);
    k_scan_write<<<nb, SCAN_BS, 0, stream>>>(degi, bsums, row_ptr, n, total);
    k_fill<<<(E + 255) / 256, 256, 0, stream>>>(src, dst, row_ptr, fill_c, col, E);

    int gemm_grid = (n + 127) / 128;
    int agg_grid  = (n + 3) / 4;

    // layer 1: h = x@W1 ; y = relu(Ah + b1)
    k_gemm<<<gemm_grid, 256, 0, stream>>>(x, W1, h_buf, n);
    k_agg<<<agg_grid, 256, 0, stream>>>(h_buf, row_ptr, col, dinv, b1, y_buf, n, 1);
    // layer 2: h2 = y@W2 ; out = Ah2 + b2
    k_gemm<<<gemm_grid, 256, 0, stream>>>(y_buf, W2, h_buf, n);
    k_agg<<<agg_grid, 256, 0, stream>>>(h_buf, row_ptr, col, dinv, b2, out, n, 0);
}

// Round 2
// 602.314 us; speedup vs baseline: 1.1673x; 1.1673x over previous
//
#include <hip/hip_runtime.h>

#define D 128

// ---------------- degree / init ----------------
__global__ void k_init(int* __restrict__ degi, int* __restrict__ fill_ctr, int n) {
    int i = blockIdx.x * blockDim.x + threadIdx.x;
    if (i < n) { degi[i] = 1; fill_ctr[i] = 0; }   // deg starts at 1 (self-loop)
}

__global__ void k_count(const int* __restrict__ dst, int* __restrict__ degi, int E) {
    int e = blockIdx.x * blockDim.x + threadIdx.x;
    if (e < E) atomicAdd(&degi[dst[e]], 1);
}

__global__ void k_dinv(const int* __restrict__ degi, float* __restrict__ dinv, int n) {
    int i = blockIdx.x * blockDim.x + threadIdx.x;
    if (i < n) dinv[i] = rsqrtf((float)degi[i]);   // deg >= 1 always (self-loop)
}

// ---------------- exclusive scan of edge counts (degi[i]-1) over n+1 elems ----------------
#define SCAN_BS 256
#define SCAN_ITEMS 4
#define SCAN_CHUNK (SCAN_BS * SCAN_ITEMS)

__device__ inline int count_at(const int* degi, int i, int n) {
    return (i < n) ? (degi[i] - 1) : 0;
}

__global__ void k_scan_partial(const int* __restrict__ degi, int* __restrict__ blockSums,
                               int n, int total) {
    __shared__ int s[SCAN_BS];
    int t = threadIdx.x;
    int base = blockIdx.x * SCAN_CHUNK + t * SCAN_ITEMS;
    int sum = 0;
    for (int j = 0; j < SCAN_ITEMS; j++) {
        int idx = base + j;
        if (idx < total) sum += count_at(degi, idx, n);
    }
    s[t] = sum; __syncthreads();
    for (int off = 1; off < SCAN_BS; off <<= 1) {
        int v = (t >= off) ? s[t - off] : 0;
        __syncthreads();
        s[t] += v;
        __syncthreads();
    }
    if (t == SCAN_BS - 1) blockSums[blockIdx.x] = s[t];
}

__global__ void k_scan_sums(int* __restrict__ blockSums, int nb) {
    __shared__ int s[1024];
    int t = threadIdx.x;
    int mine = (t < nb) ? blockSums[t] : 0;
    s[t] = mine; __syncthreads();
    for (int off = 1; off < 1024; off <<= 1) {
        int v = (t >= off) ? s[t - off] : 0;
        __syncthreads();
        s[t] += v;
        __syncthreads();
    }
    if (t < nb) blockSums[t] = s[t] - mine;   // exclusive
}

__global__ void k_scan_write(const int* __restrict__ degi, const int* __restrict__ blockSums,
                             int* __restrict__ row_ptr, int n, int total) {
    __shared__ int s[SCAN_BS];
    int t = threadIdx.x;
    int base = blockIdx.x * SCAN_CHUNK + t * SCAN_ITEMS;
    int c[SCAN_ITEMS];
    int sum = 0;
    for (int j = 0; j < SCAN_ITEMS; j++) {
        int idx = base + j;
        c[j] = (idx < total) ? count_at(degi, idx, n) : 0;
        sum += c[j];
    }
    int mine = sum;
    s[t] = sum; __syncthreads();
    for (int off = 1; off < SCAN_BS; off <<= 1) {
        int v = (t >= off) ? s[t - off] : 0;
        __syncthreads();
        s[t] += v;
        __syncthreads();
    }
    int off0 = blockSums[blockIdx.x] + (s[t] - mine);
    for (int j = 0; j < SCAN_ITEMS; j++) {
        int idx = base + j;
        if (idx < total) row_ptr[idx] = off0;
        off0 += c[j];
    }
}

__global__ void k_fill(const int* __restrict__ src, const int* __restrict__ dst,
                       const int* __restrict__ row_ptr, int* __restrict__ fill_ctr,
                       int* __restrict__ col, int E) {
    int e = blockIdx.x * blockDim.x + threadIdx.x;
    if (e < E) {
        int d = dst[e];
        int pos = row_ptr[d] + atomicAdd(&fill_ctr[d], 1);
        col[pos] = src[e];
    }
}

// ---------------- fp32 SGEMM: Y[M,128] = scale[r] * (X[M,128] @ W[128,128]) ----------------
// 128x128 block tile, 16x16 threads, 8x8 per-thread register tile, K-chunks of 32.
__global__ __launch_bounds__(256) void k_gemm(const float* __restrict__ X,
                                              const float* __restrict__ W,
                                              const float* __restrict__ scale,
                                              float* __restrict__ Y, int M) {
    __shared__ float XsT[32][132];   // transposed X tile, padded (stride 132 breaks conflicts)
    __shared__ float Ws[32][128];
    int t = threadIdx.x;
    int tx = t & 15, ty = t >> 4;
    int block_row = blockIdx.x * 128;
    float acc[8][8];
#pragma unroll
    for (int i = 0; i < 8; i++)
#pragma unroll
        for (int j = 0; j < 8; j++) acc[i][j] = 0.f;

    for (int kc = 0; kc < 128; kc += 32) {
#pragma unroll
        for (int i = 0; i < 4; i++) {            // stage X chunk (transposed)
            int idx = t + i * 256;               // 0..1023 float4 slots
            int r = idx >> 3;                    // 0..127 row in tile
            int kk = (idx & 7) << 2;             // 0..28 k offset
            int gr = block_row + r;
            float4 v = make_float4(0.f, 0.f, 0.f, 0.f);
            if (gr < M) v = *(const float4*)(X + (size_t)gr * D + kc + kk);
            XsT[kk + 0][r] = v.x; XsT[kk + 1][r] = v.y;
            XsT[kk + 2][r] = v.z; XsT[kk + 3][r] = v.w;
        }
#pragma unroll
        for (int i = 0; i < 4; i++) {            // stage W chunk (natural layout)
            int idx = t + i * 256;
            int k = idx >> 5;                    // 0..31
            int c = (idx & 31) << 2;             // 0..124
            *(float4*)&Ws[k][c] = *(const float4*)(W + (size_t)(kc + k) * D + c);
        }
        __syncthreads();
#pragma unroll
        for (int k = 0; k < 32; k++) {
            float a[8], b[8];
            *(float4*)&a[0] = *(const float4*)&XsT[k][ty * 8];
            *(float4*)&a[4] = *(const float4*)&XsT[k][ty * 8 + 4];
            *(float4*)&b[0] = *(const float4*)&Ws[k][tx * 8];
            *(float4*)&b[4] = *(const float4*)&Ws[k][tx * 8 + 4];
#pragma unroll
            for (int i = 0; i < 8; i++)
#pragma unroll
                for (int j = 0; j < 8; j++)
                    acc[i][j] = fmaf(a[i], b[j], acc[i][j]);
        }
        __syncthreads();
    }
#pragma unroll
    for (int i = 0; i < 8; i++) {
        int gr = block_row + ty * 8 + i;
        if (gr < M) {
            float sc = scale[gr];                // fold dinv into H: H' = dinv[r] * (X@W)
            float4 o0 = make_float4(sc * acc[i][0], sc * acc[i][1], sc * acc[i][2], sc * acc[i][3]);
            float4 o1 = make_float4(sc * acc[i][4], sc * acc[i][5], sc * acc[i][6], sc * acc[i][7]);
            *(float4*)(Y + (size_t)gr * D + tx * 8) = o0;
            *(float4*)(Y + (size_t)gr * D + tx * 8 + 4) = o1;
        }
    }
}

// ---------------- pull aggregation on pre-scaled H':
//   Y[d] = dinv[d] * (H'[d] + sum_{s in row d} H'[s]) + b   (optional relu)
// One wave per node. Half-wave (32 lanes x float4 = 512B) per edge -> 2 chains;
// 2x unroll per chain -> 4 independent row-gathers in flight per wave.
__global__ __launch_bounds__(256) void k_agg(const float* __restrict__ H,
                                             const int* __restrict__ row_ptr,
                                             const int* __restrict__ col,
                                             const float* __restrict__ dinv,
                                             const float* __restrict__ bias,
                                             float* __restrict__ Y, int n, int do_relu) {
    int node = blockIdx.x * 4 + (threadIdx.x >> 6);
    int lane = threadIdx.x & 63;
    int half = lane >> 5;        // which edge chain
    int l32  = lane & 31;        // float4 slot: cols 4*l32 .. 4*l32+3
    if (node >= n) return;

    int start = row_ptr[node];
    int end   = row_ptr[node + 1];

    float4 a0 = make_float4(0.f, 0.f, 0.f, 0.f);
    float4 a1 = make_float4(0.f, 0.f, 0.f, 0.f);

    if (half == 0) {             // self-loop row in chain 0
        a0 = ((const float4*)(H + (size_t)node * D))[l32];
    }

    int e = start + half;
    for (; e + 2 < end; e += 4) {
        int s0 = col[e];
        int s1 = col[e + 2];
        float4 h0 = ((const float4*)(H + (size_t)s0 * D))[l32];
        float4 h1 = ((const float4*)(H + (size_t)s1 * D))[l32];
        a0.x += h0.x; a0.y += h0.y; a0.z += h0.z; a0.w += h0.w;
        a1.x += h1.x; a1.y += h1.y; a1.z += h1.z; a1.w += h1.w;
    }
    if (e < end) {
        int s0 = col[e];
        float4 h0 = ((const float4*)(H + (size_t)s0 * D))[l32];
        a0.x += h0.x; a0.y += h0.y; a0.z += h0.z; a0.w += h0.w;
    }

    float4 acc;
    acc.x = a0.x + a1.x; acc.y = a0.y + a1.y;
    acc.z = a0.z + a1.z; acc.w = a0.w + a1.w;

    // combine the two half-wave chains (lane ^ 32)
    acc.x += __shfl_xor(acc.x, 32, 64);
    acc.y += __shfl_xor(acc.y, 32, 64);
    acc.z += __shfl_xor(acc.z, 32, 64);
    acc.w += __shfl_xor(acc.w, 32, 64);

    if (half == 0) {
        float di = dinv[node];
        float4 bb = ((const float4*)bias)[l32];
        acc.x = fmaf(di, acc.x, bb.x);
        acc.y = fmaf(di, acc.y, bb.y);
        acc.z = fmaf(di, acc.z, bb.z);
        acc.w = fmaf(di, acc.w, bb.w);
        if (do_relu) {
            acc.x = fmaxf(acc.x, 0.f); acc.y = fmaxf(acc.y, 0.f);
            acc.z = fmaxf(acc.z, 0.f); acc.w = fmaxf(acc.w, 0.f);
        }
        ((float4*)(Y + (size_t)node * D))[l32] = acc;
    }
}

// ---------------- host ----------------
extern "C" void kernel_launch(void* const* d_in, const int* in_sizes, int n_in,
                              void* d_out, int out_size, void* d_ws, size_t ws_size,
                              hipStream_t stream) {
    const float* x  = (const float*)d_in[0];
    const int*   ei = (const int*)d_in[1];
    const float* W1 = (const float*)d_in[2];
    const float* b1 = (const float*)d_in[3];
    const float* W2 = (const float*)d_in[4];
    const float* b2 = (const float*)d_in[5];
    float* out = (float*)d_out;

    int n = in_sizes[0] / D;       // 100000
    int E = in_sizes[1] / 2;       // 1600000
    const int* src = ei;
    const int* dst = ei + E;

    char* p = (char*)d_ws;
    float* h_buf  = (float*)p;  p += (size_t)n * D * sizeof(float);
    float* y_buf  = (float*)p;  p += (size_t)n * D * sizeof(float);
    int*   degi   = (int*)p;    p += (size_t)n * sizeof(int);
    float* dinv   = (float*)p;  p += (size_t)n * sizeof(float);
    int*   row_ptr= (int*)p;    p += (size_t)(n + 1) * sizeof(int);
    int*   fill_c = (int*)p;    p += (size_t)n * sizeof(int);
    int*   bsums  = (int*)p;    p += 1024 * sizeof(int);
    int*   col    = (int*)p;    p += (size_t)E * sizeof(int);

    int total = n + 1;
    int nb = (total + SCAN_CHUNK - 1) / SCAN_CHUNK;   // 98 for n=100000, fits 1024-thread scan

    k_init<<<(n + 255) / 256, 256, 0, stream>>>(degi, fill_c, n);
    k_count<<<(E + 255) / 256, 256, 0, stream>>>(dst, degi, E);
    k_dinv<<<(n + 255) / 256, 256, 0, stream>>>(degi, dinv, n);
    k_scan_partial<<<nb, SCAN_BS, 0, stream>>>(degi, bsums, n, total);
    k_scan_sums<<<1, 1024, 0, stream>>>(bsums, nb);
    k_scan_write<<<nb, SCAN_BS, 0, stream>>>(degi, bsums, row_ptr, n, total);
    k_fill<<<(E + 255) / 256, 256, 0, stream>>>(src, dst, row_ptr, fill_c, col, E);

    int gemm_grid = (n + 127) / 128;
    int agg_grid  = (n + 3) / 4;

    // layer 1: h' = dinv * (x@W1) ; y = relu(dinv * (A_sum h') + b1)
    k_gemm<<<gemm_grid, 256, 0, stream>>>(x, W1, dinv, h_buf, n);
    k_agg<<<agg_grid, 256, 0, stream>>>(h_buf, row_ptr, col, dinv, b1, y_buf, n, 1);
    // layer 2: h2' = dinv * (y@W2) ; out = dinv * (A_sum h2') + b2
    k_gemm<<<gemm_grid, 256, 0, stream>>>(y_buf, W2, dinv, h_buf, n);
    k_agg<<<agg_grid, 256, 0, stream>>>(h_buf, row_ptr, col, dinv, b2, out, n, 0);
}

// Round 3
// 469.668 us; speedup vs baseline: 1.4970x; 1.2824x over previous
//
#include <hip/hip_runtime.h>

#define D 128

typedef unsigned int uint;
typedef unsigned short ushort;

// ---------------- degree / init ----------------
__global__ void k_init(int* __restrict__ degi, int n) {
    int i = blockIdx.x * blockDim.x + threadIdx.x;
    if (i < n) degi[i] = 1;                        // deg starts at 1 (self-loop)
}

// count + record each edge's rank within its dst row (rank = old deg, starts at 1)
__global__ void k_count_rank(const int* __restrict__ dst, int* __restrict__ degi,
                             int* __restrict__ rank, int E) {
    int e = blockIdx.x * blockDim.x + threadIdx.x;
    if (e < E) rank[e] = atomicAdd(&degi[dst[e]], 1);
}

__global__ void k_dinv(const int* __restrict__ degi, float* __restrict__ dinv, int n) {
    int i = blockIdx.x * blockDim.x + threadIdx.x;
    if (i < n) dinv[i] = rsqrtf((float)degi[i]);   // deg >= 1 always (self-loop)
}

// ---------------- exclusive scan of edge counts (degi[i]-1) over n+1 elems ----------------
#define SCAN_BS 256
#define SCAN_ITEMS 4
#define SCAN_CHUNK (SCAN_BS * SCAN_ITEMS)

__device__ inline int count_at(const int* degi, int i, int n) {
    return (i < n) ? (degi[i] - 1) : 0;
}

__global__ void k_scan_partial(const int* __restrict__ degi, int* __restrict__ blockSums,
                               int n, int total) {
    __shared__ int s[SCAN_BS];
    int t = threadIdx.x;
    int base = blockIdx.x * SCAN_CHUNK + t * SCAN_ITEMS;
    int sum = 0;
    for (int j = 0; j < SCAN_ITEMS; j++) {
        int idx = base + j;
        if (idx < total) sum += count_at(degi, idx, n);
    }
    s[t] = sum; __syncthreads();
    for (int off = 1; off < SCAN_BS; off <<= 1) {
        int v = (t >= off) ? s[t - off] : 0;
        __syncthreads();
        s[t] += v;
        __syncthreads();
    }
    if (t == SCAN_BS - 1) blockSums[blockIdx.x] = s[t];
}

__global__ void k_scan_sums(int* __restrict__ blockSums, int nb) {
    __shared__ int s[1024];
    int t = threadIdx.x;
    int mine = (t < nb) ? blockSums[t] : 0;
    s[t] = mine; __syncthreads();
    for (int off = 1; off < 1024; off <<= 1) {
        int v = (t >= off) ? s[t - off] : 0;
        __syncthreads();
        s[t] += v;
        __syncthreads();
    }
    if (t < nb) blockSums[t] = s[t] - mine;   // exclusive
}

__global__ void k_scan_write(const int* __restrict__ degi, const int* __restrict__ blockSums,
                             int* __restrict__ row_ptr, int n, int total) {
    __shared__ int s[SCAN_BS];
    int t = threadIdx.x;
    int base = blockIdx.x * SCAN_CHUNK + t * SCAN_ITEMS;
    int c[SCAN_ITEMS];
    int sum = 0;
    for (int j = 0; j < SCAN_ITEMS; j++) {
        int idx = base + j;
        c[j] = (idx < total) ? count_at(degi, idx, n) : 0;
        sum += c[j];
    }
    int mine = sum;
    s[t] = sum; __syncthreads();
    for (int off = 1; off < SCAN_BS; off <<= 1) {
        int v = (t >= off) ? s[t - off] : 0;
        __syncthreads();
        s[t] += v;
        __syncthreads();
    }
    int off0 = blockSums[blockIdx.x] + (s[t] - mine);
    for (int j = 0; j < SCAN_ITEMS; j++) {
        int idx = base + j;
        if (idx < total) row_ptr[idx] = off0;
        off0 += c[j];
    }
}

// atomic-free fill using precomputed rank (rank starts at 1)
__global__ void k_fill(const int* __restrict__ src, const int* __restrict__ dst,
                       const int* __restrict__ row_ptr, const int* __restrict__ rank,
                       int* __restrict__ col, int E) {
    int e = blockIdx.x * blockDim.x + threadIdx.x;
    if (e < E) {
        int d = dst[e];
        col[row_ptr[d] + rank[e] - 1] = src[e];
    }
}

// ---------------- bf16 helpers ----------------
__device__ inline uint bf16rn(float f) {               // fp32 -> bf16 bits, round-nearest-even
    uint u = __float_as_uint(f);
    return (u + 0x7fffu + ((u >> 16) & 1u)) >> 16;
}

__device__ inline void accum_bf16x8(float* a, uint4 v) {
    a[0] += __uint_as_float(v.x << 16);
    a[1] += __uint_as_float(v.x & 0xffff0000u);
    a[2] += __uint_as_float(v.y << 16);
    a[3] += __uint_as_float(v.y & 0xffff0000u);
    a[4] += __uint_as_float(v.z << 16);
    a[5] += __uint_as_float(v.z & 0xffff0000u);
    a[6] += __uint_as_float(v.w << 16);
    a[7] += __uint_as_float(v.w & 0xffff0000u);
}

// ---------------- fp32 SGEMM: Hb[M,128](bf16) = scale[r] * (X[M,128] @ W[128,128]) ----------------
// 128x128 block tile, 16x16 threads, 8x8 per-thread register tile, K-chunks of 32.
__global__ __launch_bounds__(256) void k_gemm(const float* __restrict__ X,
                                              const float* __restrict__ W,
                                              const float* __restrict__ scale,
                                              ushort* __restrict__ Yb, int M) {
    __shared__ float XsT[32][132];   // transposed X tile, padded (stride 132 breaks conflicts)
    __shared__ float Ws[32][128];
    int t = threadIdx.x;
    int tx = t & 15, ty = t >> 4;
    int block_row = blockIdx.x * 128;
    float acc[8][8];
#pragma unroll
    for (int i = 0; i < 8; i++)
#pragma unroll
        for (int j = 0; j < 8; j++) acc[i][j] = 0.f;

    for (int kc = 0; kc < 128; kc += 32) {
#pragma unroll
        for (int i = 0; i < 4; i++) {            // stage X chunk (transposed)
            int idx = t + i * 256;               // 0..1023 float4 slots
            int r = idx >> 3;                    // 0..127 row in tile
            int kk = (idx & 7) << 2;             // 0..28 k offset
            int gr = block_row + r;
            float4 v = make_float4(0.f, 0.f, 0.f, 0.f);
            if (gr < M) v = *(const float4*)(X + (size_t)gr * D + kc + kk);
            XsT[kk + 0][r] = v.x; XsT[kk + 1][r] = v.y;
            XsT[kk + 2][r] = v.z; XsT[kk + 3][r] = v.w;
        }
#pragma unroll
        for (int i = 0; i < 4; i++) {            // stage W chunk (natural layout)
            int idx = t + i * 256;
            int k = idx >> 5;                    // 0..31
            int c = (idx & 31) << 2;             // 0..124
            *(float4*)&Ws[k][c] = *(const float4*)(W + (size_t)(kc + k) * D + c);
        }
        __syncthreads();
#pragma unroll
        for (int k = 0; k < 32; k++) {
            float a[8], b[8];
            *(float4*)&a[0] = *(const float4*)&XsT[k][ty * 8];
            *(float4*)&a[4] = *(const float4*)&XsT[k][ty * 8 + 4];
            *(float4*)&b[0] = *(const float4*)&Ws[k][tx * 8];
            *(float4*)&b[4] = *(const float4*)&Ws[k][tx * 8 + 4];
#pragma unroll
            for (int i = 0; i < 8; i++)
#pragma unroll
                for (int j = 0; j < 8; j++)
                    acc[i][j] = fmaf(a[i], b[j], acc[i][j]);
        }
        __syncthreads();
    }
#pragma unroll
    for (int i = 0; i < 8; i++) {
        int gr = block_row + ty * 8 + i;
        if (gr < M) {
            float sc = scale[gr];                // fold dinv into H: H' = dinv[r] * (X@W)
            uint4 pk;
            pk.x = bf16rn(sc * acc[i][0]) | (bf16rn(sc * acc[i][1]) << 16);
            pk.y = bf16rn(sc * acc[i][2]) | (bf16rn(sc * acc[i][3]) << 16);
            pk.z = bf16rn(sc * acc[i][4]) | (bf16rn(sc * acc[i][5]) << 16);
            pk.w = bf16rn(sc * acc[i][6]) | (bf16rn(sc * acc[i][7]) << 16);
            *(uint4*)(Yb + (size_t)gr * D + tx * 8) = pk;   // 8 bf16 = 16B
        }
    }
}

// ---------------- pull aggregation on pre-scaled bf16 H':
//   Y[d] = dinv[d] * (H'[d] + sum_{s in row d} H'[s]) + b   (optional relu)
// One wave per node. Quarter-wave (16 lanes x 16B = 256B) per edge row -> 4 chains;
// 2x unroll per chain -> 8 independent row-gathers in flight per wave.
__global__ __launch_bounds__(256) void k_agg(const ushort* __restrict__ Hb,
                                             const int* __restrict__ row_ptr,
                                             const int* __restrict__ col,
                                             const float* __restrict__ dinv,
                                             const float* __restrict__ bias,
                                             float* __restrict__ Y, int n, int do_relu) {
    int node = blockIdx.x * 4 + (threadIdx.x >> 6);
    int lane = threadIdx.x & 63;
    int chain = lane >> 4;       // 0..3: which edge chain
    int l16   = lane & 15;       // 16B slot: bf16 cols 8*l16 .. 8*l16+7
    if (node >= n) return;

    int start = row_ptr[node];
    int end   = row_ptr[node + 1];

    float a0[8], a1[8];
#pragma unroll
    for (int k = 0; k < 8; k++) { a0[k] = 0.f; a1[k] = 0.f; }

    if (chain == 0) {            // self-loop row in chain 0
        uint4 v = ((const uint4*)(Hb + (size_t)node * D))[l16];
        accum_bf16x8(a0, v);
    }

    int e = start + chain;
    for (; e + 4 < end; e += 8) {
        int s0 = col[e];
        int s1 = col[e + 4];
        uint4 v0 = ((const uint4*)(Hb + (size_t)s0 * D))[l16];
        uint4 v1 = ((const uint4*)(Hb + (size_t)s1 * D))[l16];
        accum_bf16x8(a0, v0);
        accum_bf16x8(a1, v1);
    }
    if (e < end) {               // at most one tail element per chain
        int s0 = col[e];
        uint4 v0 = ((const uint4*)(Hb + (size_t)s0 * D))[l16];
        accum_bf16x8(a0, v0);
    }

    float acc[8];
#pragma unroll
    for (int k = 0; k < 8; k++) {
        float v = a0[k] + a1[k];
        v += __shfl_xor(v, 16, 64);   // combine chains 0<->1, 2<->3
        v += __shfl_xor(v, 32, 64);   // combine pairs
        acc[k] = v;
    }

    if (chain == 0) {            // lanes 0..15 hold the full row
        float di = dinv[node];
        const float4* bp = (const float4*)bias + l16 * 2;
        float4 b0 = bp[0], b1 = bp[1];
        float4 o0, o1;
        o0.x = fmaf(di, acc[0], b0.x); o0.y = fmaf(di, acc[1], b0.y);
        o0.z = fmaf(di, acc[2], b0.z); o0.w = fmaf(di, acc[3], b0.w);
        o1.x = fmaf(di, acc[4], b1.x); o1.y = fmaf(di, acc[5], b1.y);
        o1.z = fmaf(di, acc[6], b1.z); o1.w = fmaf(di, acc[7], b1.w);
        if (do_relu) {
            o0.x = fmaxf(o0.x, 0.f); o0.y = fmaxf(o0.y, 0.f);
            o0.z = fmaxf(o0.z, 0.f); o0.w = fmaxf(o0.w, 0.f);
            o1.x = fmaxf(o1.x, 0.f); o1.y = fmaxf(o1.y, 0.f);
            o1.z = fmaxf(o1.z, 0.f); o1.w = fmaxf(o1.w, 0.f);
        }
        float4* yp = (float4*)(Y + (size_t)node * D) + l16 * 2;
        yp[0] = o0;
        yp[1] = o1;
    }
}

// ---------------- host ----------------
extern "C" void kernel_launch(void* const* d_in, const int* in_sizes, int n_in,
                              void* d_out, int out_size, void* d_ws, size_t ws_size,
                              hipStream_t stream) {
    const float* x  = (const float*)d_in[0];
    const int*   ei = (const int*)d_in[1];
    const float* W1 = (const float*)d_in[2];
    const float* b1 = (const float*)d_in[3];
    const float* W2 = (const float*)d_in[4];
    const float* b2 = (const float*)d_in[5];
    float* out = (float*)d_out;

    int n = in_sizes[0] / D;       // 100000
    int E = in_sizes[1] / 2;       // 1600000
    const int* src = ei;
    const int* dst = ei + E;

    char* p = (char*)d_ws;
    ushort* h_buf = (ushort*)p; p += (size_t)n * D * sizeof(ushort);   // bf16 H'
    float* y_buf  = (float*)p;  p += (size_t)n * D * sizeof(float);
    int*   degi   = (int*)p;    p += (size_t)n * sizeof(int);
    float* dinv   = (float*)p;  p += (size_t)n * sizeof(float);
    int*   row_ptr= (int*)p;    p += (size_t)(n + 1) * sizeof(int);
    int*   bsums  = (int*)p;    p += 1024 * sizeof(int);
    int*   rank   = (int*)p;    p += (size_t)E * sizeof(int);
    int*   col    = (int*)p;    p += (size_t)E * sizeof(int);

    int total = n + 1;
    int nb = (total + SCAN_CHUNK - 1) / SCAN_CHUNK;   // 98 for n=100000, fits 1024-thread scan

    k_init<<<(n + 255) / 256, 256, 0, stream>>>(degi, n);
    k_count_rank<<<(E + 255) / 256, 256, 0, stream>>>(dst, degi, rank, E);
    k_dinv<<<(n + 255) / 256, 256, 0, stream>>>(degi, dinv, n);
    k_scan_partial<<<nb, SCAN_BS, 0, stream>>>(degi, bsums, n, total);
    k_scan_sums<<<1, 1024, 0, stream>>>(bsums, nb);
    k_scan_write<<<nb, SCAN_BS, 0, stream>>>(degi, bsums, row_ptr, n, total);
    k_fill<<<(E + 255) / 256, 256, 0, stream>>>(src, dst, row_ptr, rank, col, E);

    int gemm_grid = (n + 127) / 128;
    int agg_grid  = (n + 3) / 4;

    // layer 1: h' = bf16(dinv * (x@W1)) ; y = relu(dinv * (A_sum h') + b1)
    k_gemm<<<gemm_grid, 256, 0, stream>>>(x, W1, dinv, h_buf, n);
    k_agg<<<agg_grid, 256, 0, stream>>>(h_buf, row_ptr, col, dinv, b1, y_buf, n, 1);
    // layer 2: h2' = bf16(dinv * (y@W2)) ; out = dinv * (A_sum h2') + b2
    k_gemm<<<gemm_grid, 256, 0, stream>>>(y_buf, W2, dinv, h_buf, n);
    k_agg<<<agg_grid, 256, 0, stream>>>(h_buf, row_ptr, col, dinv, b2, out, n, 0);
}

// Round 4
// 389.032 us; speedup vs baseline: 1.8073x; 1.2073x over previous
//
#include <hip/hip_runtime.h>

#define D 128

typedef unsigned int uint;
typedef unsigned short ushort;
typedef __attribute__((ext_vector_type(8))) short bf16x8_t;   // 8 bf16 = 4 VGPRs
typedef __attribute__((ext_vector_type(4))) float f32x4_t;    // MFMA accumulator

// ---------------- degree / init ----------------
__global__ void k_init(int* __restrict__ degi, int n) {
    int i = blockIdx.x * blockDim.x + threadIdx.x;
    if (i < n) degi[i] = 1;                        // deg starts at 1 (self-loop)
}

// count + record each edge's rank within its dst row (rank = old deg, starts at 1)
__global__ void k_count_rank(const int* __restrict__ dst, int* __restrict__ degi,
                             int* __restrict__ rank, int E) {
    int e = blockIdx.x * blockDim.x + threadIdx.x;
    if (e < E) rank[e] = atomicAdd(&degi[dst[e]], 1);
}

__global__ void k_dinv(const int* __restrict__ degi, float* __restrict__ dinv, int n) {
    int i = blockIdx.x * blockDim.x + threadIdx.x;
    if (i < n) dinv[i] = rsqrtf((float)degi[i]);   // deg >= 1 always (self-loop)
}

// ---------------- exclusive scan of edge counts (degi[i]-1) over n+1 elems ----------------
#define SCAN_BS 256
#define SCAN_ITEMS 4
#define SCAN_CHUNK (SCAN_BS * SCAN_ITEMS)

__device__ inline int count_at(const int* degi, int i, int n) {
    return (i < n) ? (degi[i] - 1) : 0;
}

__global__ void k_scan_partial(const int* __restrict__ degi, int* __restrict__ blockSums,
                               int n, int total) {
    __shared__ int s[SCAN_BS];
    int t = threadIdx.x;
    int base = blockIdx.x * SCAN_CHUNK + t * SCAN_ITEMS;
    int sum = 0;
    for (int j = 0; j < SCAN_ITEMS; j++) {
        int idx = base + j;
        if (idx < total) sum += count_at(degi, idx, n);
    }
    s[t] = sum; __syncthreads();
    for (int off = 1; off < SCAN_BS; off <<= 1) {
        int v = (t >= off) ? s[t - off] : 0;
        __syncthreads();
        s[t] += v;
        __syncthreads();
    }
    if (t == SCAN_BS - 1) blockSums[blockIdx.x] = s[t];
}

__global__ void k_scan_sums(int* __restrict__ blockSums, int nb) {
    __shared__ int s[1024];
    int t = threadIdx.x;
    int mine = (t < nb) ? blockSums[t] : 0;
    s[t] = mine; __syncthreads();
    for (int off = 1; off < 1024; off <<= 1) {
        int v = (t >= off) ? s[t - off] : 0;
        __syncthreads();
        s[t] += v;
        __syncthreads();
    }
    if (t < nb) blockSums[t] = s[t] - mine;   // exclusive
}

__global__ void k_scan_write(const int* __restrict__ degi, const int* __restrict__ blockSums,
                             int* __restrict__ row_ptr, int n, int total) {
    __shared__ int s[SCAN_BS];
    int t = threadIdx.x;
    int base = blockIdx.x * SCAN_CHUNK + t * SCAN_ITEMS;
    int c[SCAN_ITEMS];
    int sum = 0;
    for (int j = 0; j < SCAN_ITEMS; j++) {
        int idx = base + j;
        c[j] = (idx < total) ? count_at(degi, idx, n) : 0;
        sum += c[j];
    }
    int mine = sum;
    s[t] = sum; __syncthreads();
    for (int off = 1; off < SCAN_BS; off <<= 1) {
        int v = (t >= off) ? s[t - off] : 0;
        __syncthreads();
        s[t] += v;
        __syncthreads();
    }
    int off0 = blockSums[blockIdx.x] + (s[t] - mine);
    for (int j = 0; j < SCAN_ITEMS; j++) {
        int idx = base + j;
        if (idx < total) row_ptr[idx] = off0;
        off0 += c[j];
    }
}

// atomic-free fill using precomputed rank (rank starts at 1)
__global__ void k_fill(const int* __restrict__ src, const int* __restrict__ dst,
                       const int* __restrict__ row_ptr, const int* __restrict__ rank,
                       int* __restrict__ col, int E) {
    int e = blockIdx.x * blockDim.x + threadIdx.x;
    if (e < E) {
        int d = dst[e];
        col[row_ptr[d] + rank[e] - 1] = src[e];
    }
}

// ---------------- bf16 helpers ----------------
__device__ inline uint bf16rn(float f) {               // fp32 -> bf16 bits, round-nearest-even
    uint u = __float_as_uint(f);
    return (u + 0x7fffu + ((u >> 16) & 1u)) >> 16;
}

__device__ inline void accum_bf16x8(float* a, uint4 v) {
    a[0] += __uint_as_float(v.x << 16);
    a[1] += __uint_as_float(v.x & 0xffff0000u);
    a[2] += __uint_as_float(v.y << 16);
    a[3] += __uint_as_float(v.y & 0xffff0000u);
    a[4] += __uint_as_float(v.z << 16);
    a[5] += __uint_as_float(v.z & 0xffff0000u);
    a[6] += __uint_as_float(v.w << 16);
    a[7] += __uint_as_float(v.w & 0xffff0000u);
}

// ---------------- W prep: Wt_hi/Wt_lo[n][k] (bf16 split) from W[k][n] fp32 ----------------
__global__ void k_prep_w(const float* __restrict__ W, ushort* __restrict__ Wh,
                         ushort* __restrict__ Wl) {
    int i = blockIdx.x * blockDim.x + threadIdx.x;   // 16384
    int k = i >> 7, n = i & 127;
    float w = W[k * D + n];
    uint hb = bf16rn(w);
    float hf = __uint_as_float(hb << 16);
    uint lb = bf16rn(w - hf);
    Wh[n * D + k] = (ushort)hb;
    Wl[n * D + k] = (ushort)lb;
}

// ---------------- MFMA GEMM: Hb[M,128](bf16) = dinv[r] * (A[M,128] @ W[128,128]) ----------------
// A_FP32: A is fp32, split hi/lo -> 3 passes (AhWh + AlWh + AhWl), error ~2^-18.
// else:   A is bf16 (exact)      -> 2 passes (AhWh + AhWl).
// 128x128 block tile, BK=64, 4 waves x (64x64), LDS stride 72 bf16 (2-way = free).
template <bool A_FP32>
__global__ __launch_bounds__(256, 2) void k_gemm_mfma(const void* __restrict__ A,
                                                      const ushort* __restrict__ Wth,
                                                      const ushort* __restrict__ Wtl,
                                                      const float* __restrict__ dinv,
                                                      ushort* __restrict__ Yb, int M) {
    constexpr int STR = 72;                          // LDS row stride in bf16
    constexpr int TILE = 128 * STR;                  // 9216 ushorts per tile
    __shared__ ushort lds[A_FP32 ? 4 * TILE : 3 * TILE];
    ushort* Ah = lds;
    ushort* Wh = lds + TILE;
    ushort* Wl = lds + 2 * TILE;
    ushort* Al = A_FP32 ? (lds + 3 * TILE) : nullptr;

    int t = threadIdx.x;
    int lane = t & 63, wave = t >> 6;
    int quad = lane >> 4, l16 = lane & 15;
    int m_off = (wave & 1) * 64;                     // wave's 64x64 sub-tile
    int n_off = (wave >> 1) * 64;
    int block_row = blockIdx.x * 128;

    f32x4_t acc[4][4];
#pragma unroll
    for (int mt = 0; mt < 4; mt++)
#pragma unroll
        for (int nt = 0; nt < 4; nt++) acc[mt][nt] = (f32x4_t){0.f, 0.f, 0.f, 0.f};

    for (int kc = 0; kc < 128; kc += 64) {
        // ---- stage A ----
        if (A_FP32) {
            const float* Af = (const float*)A;
#pragma unroll
            for (int it = 0; it < 8; it++) {
                int s = t + it * 256;                // 2048 float4 slots
                int row = s >> 4, kl = (s & 15) * 4;
                int gr = block_row + row;
                float4 v = make_float4(0.f, 0.f, 0.f, 0.f);
                if (gr < M) v = *(const float4*)(Af + (size_t)gr * D + kc + kl);
                ushort4 h, l;
                uint hb, lb; float hf;
                hb = bf16rn(v.x); hf = __uint_as_float(hb << 16); lb = bf16rn(v.x - hf);
                h.x = (ushort)hb; l.x = (ushort)lb;
                hb = bf16rn(v.y); hf = __uint_as_float(hb << 16); lb = bf16rn(v.y - hf);
                h.y = (ushort)hb; l.y = (ushort)lb;
                hb = bf16rn(v.z); hf = __uint_as_float(hb << 16); lb = bf16rn(v.z - hf);
                h.z = (ushort)hb; l.z = (ushort)lb;
                hb = bf16rn(v.w); hf = __uint_as_float(hb << 16); lb = bf16rn(v.w - hf);
                h.w = (ushort)hb; l.w = (ushort)lb;
                *(ushort4*)&Ah[row * STR + kl] = h;
                *(ushort4*)&Al[row * STR + kl] = l;
            }
        } else {
            const ushort* Ab = (const ushort*)A;
#pragma unroll
            for (int it = 0; it < 4; it++) {
                int s = t + it * 256;                // 1024 16B slots
                int row = s >> 3, kl = (s & 7) * 8;
                int gr = block_row + row;
                uint4 v = make_uint4(0u, 0u, 0u, 0u);
                if (gr < M) v = *(const uint4*)(Ab + (size_t)gr * D + kc + kl);
                *(uint4*)&Ah[row * STR + kl] = v;
            }
        }
        // ---- stage W (pre-transposed bf16 hi/lo) ----
#pragma unroll
        for (int it = 0; it < 4; it++) {
            int s = t + it * 256;
            int nrow = s >> 3, kl = (s & 7) * 8;
            *(uint4*)&Wh[nrow * STR + kl] = *(const uint4*)(Wth + nrow * D + kc + kl);
            *(uint4*)&Wl[nrow * STR + kl] = *(const uint4*)(Wtl + nrow * D + kc + kl);
        }
        __syncthreads();

        // ---- MFMA over 2 k-steps of 32 ----
#pragma unroll
        for (int ks = 0; ks < 2; ks++) {
            int kf = ks * 32 + quad * 8;
            bf16x8_t ah[4], bh[4], bl[4];
#pragma unroll
            for (int mt = 0; mt < 4; mt++)
                ah[mt] = *(const bf16x8_t*)&Ah[(m_off + mt * 16 + l16) * STR + kf];
#pragma unroll
            for (int nt = 0; nt < 4; nt++) {
                bh[nt] = *(const bf16x8_t*)&Wh[(n_off + nt * 16 + l16) * STR + kf];
                bl[nt] = *(const bf16x8_t*)&Wl[(n_off + nt * 16 + l16) * STR + kf];
            }
            if (A_FP32) {
                bf16x8_t al[4];
#pragma unroll
                for (int mt = 0; mt < 4; mt++)
                    al[mt] = *(const bf16x8_t*)&Al[(m_off + mt * 16 + l16) * STR + kf];
#pragma unroll
                for (int mt = 0; mt < 4; mt++)
#pragma unroll
                    for (int nt = 0; nt < 4; nt++) {
                        acc[mt][nt] = __builtin_amdgcn_mfma_f32_16x16x32_bf16(ah[mt], bh[nt], acc[mt][nt], 0, 0, 0);
                        acc[mt][nt] = __builtin_amdgcn_mfma_f32_16x16x32_bf16(al[mt], bh[nt], acc[mt][nt], 0, 0, 0);
                        acc[mt][nt] = __builtin_amdgcn_mfma_f32_16x16x32_bf16(ah[mt], bl[nt], acc[mt][nt], 0, 0, 0);
                    }
            } else {
#pragma unroll
                for (int mt = 0; mt < 4; mt++)
#pragma unroll
                    for (int nt = 0; nt < 4; nt++) {
                        acc[mt][nt] = __builtin_amdgcn_mfma_f32_16x16x32_bf16(ah[mt], bh[nt], acc[mt][nt], 0, 0, 0);
                        acc[mt][nt] = __builtin_amdgcn_mfma_f32_16x16x32_bf16(ah[mt], bl[nt], acc[mt][nt], 0, 0, 0);
                    }
            }
        }
        __syncthreads();
    }

    // ---- epilogue: C layout col=lane&15, row=quad*4+reg; scale by dinv, pack bf16 ----
#pragma unroll
    for (int mt = 0; mt < 4; mt++) {
#pragma unroll
        for (int reg = 0; reg < 4; reg++) {
            int gr = block_row + m_off + mt * 16 + quad * 4 + reg;
            if (gr < M) {
                float di = dinv[gr];
#pragma unroll
                for (int nt = 0; nt < 4; nt++) {
                    int colg = n_off + nt * 16 + l16;
                    Yb[(size_t)gr * D + colg] = (ushort)bf16rn(di * acc[mt][nt][reg]);
                }
            }
        }
    }
}

// ---------------- pull aggregation on pre-scaled bf16 H':
//   Y[d] = dinv[d] * (H'[d] + sum_{s in row d} H'[s]) + b   (optional relu; optional bf16 out)
// One wave per node. Quarter-wave (16 lanes x 16B = 256B) per edge row -> 4 chains;
// 2x unroll per chain -> 8 independent row-gathers in flight per wave.
__global__ __launch_bounds__(256) void k_agg(const ushort* __restrict__ Hb,
                                             const int* __restrict__ row_ptr,
                                             const int* __restrict__ col,
                                             const float* __restrict__ dinv,
                                             const float* __restrict__ bias,
                                             float* __restrict__ Yf, ushort* __restrict__ Yb,
                                             int n, int do_relu, int out_bf16) {
    int node = blockIdx.x * 4 + (threadIdx.x >> 6);
    int lane = threadIdx.x & 63;
    int chain = lane >> 4;       // 0..3: which edge chain
    int l16   = lane & 15;       // 16B slot: bf16 cols 8*l16 .. 8*l16+7
    if (node >= n) return;

    int start = row_ptr[node];
    int end   = row_ptr[node + 1];

    float a0[8], a1[8];
#pragma unroll
    for (int k = 0; k < 8; k++) { a0[k] = 0.f; a1[k] = 0.f; }

    if (chain == 0) {            // self-loop row in chain 0
        uint4 v = ((const uint4*)(Hb + (size_t)node * D))[l16];
        accum_bf16x8(a0, v);
    }

    int e = start + chain;
    for (; e + 4 < end; e += 8) {
        int s0 = col[e];
        int s1 = col[e + 4];
        uint4 v0 = ((const uint4*)(Hb + (size_t)s0 * D))[l16];
        uint4 v1 = ((const uint4*)(Hb + (size_t)s1 * D))[l16];
        accum_bf16x8(a0, v0);
        accum_bf16x8(a1, v1);
    }
    if (e < end) {               // at most one tail element per chain
        int s0 = col[e];
        uint4 v0 = ((const uint4*)(Hb + (size_t)s0 * D))[l16];
        accum_bf16x8(a0, v0);
    }

    float acc[8];
#pragma unroll
    for (int k = 0; k < 8; k++) {
        float v = a0[k] + a1[k];
        v += __shfl_xor(v, 16, 64);   // combine chains 0<->1, 2<->3
        v += __shfl_xor(v, 32, 64);   // combine pairs
        acc[k] = v;
    }

    if (chain == 0) {            // lanes 0..15 hold the full row (cols 8*l16..8*l16+7)
        float di = dinv[node];
        const float4* bp = (const float4*)bias + l16 * 2;
        float4 b0 = bp[0], b1 = bp[1];
        float o[8];
        o[0] = fmaf(di, acc[0], b0.x); o[1] = fmaf(di, acc[1], b0.y);
        o[2] = fmaf(di, acc[2], b0.z); o[3] = fmaf(di, acc[3], b0.w);
        o[4] = fmaf(di, acc[4], b1.x); o[5] = fmaf(di, acc[5], b1.y);
        o[6] = fmaf(di, acc[6], b1.z); o[7] = fmaf(di, acc[7], b1.w);
        if (do_relu) {
#pragma unroll
            for (int k = 0; k < 8; k++) o[k] = fmaxf(o[k], 0.f);
        }
        if (out_bf16) {
            uint4 pk;
            pk.x = bf16rn(o[0]) | (bf16rn(o[1]) << 16);
            pk.y = bf16rn(o[2]) | (bf16rn(o[3]) << 16);
            pk.z = bf16rn(o[4]) | (bf16rn(o[5]) << 16);
            pk.w = bf16rn(o[6]) | (bf16rn(o[7]) << 16);
            ((uint4*)(Yb + (size_t)node * D))[l16] = pk;
        } else {
            float4* yp = (float4*)(Yf + (size_t)node * D) + l16 * 2;
            yp[0] = make_float4(o[0], o[1], o[2], o[3]);
            yp[1] = make_float4(o[4], o[5], o[6], o[7]);
        }
    }
}

// ---------------- host ----------------
extern "C" void kernel_launch(void* const* d_in, const int* in_sizes, int n_in,
                              void* d_out, int out_size, void* d_ws, size_t ws_size,
                              hipStream_t stream) {
    const float* x  = (const float*)d_in[0];
    const int*   ei = (const int*)d_in[1];
    const float* W1 = (const float*)d_in[2];
    const float* b1 = (const float*)d_in[3];
    const float* W2 = (const float*)d_in[4];
    const float* b2 = (const float*)d_in[5];
    float* out = (float*)d_out;

    int n = in_sizes[0] / D;       // 100000
    int E = in_sizes[1] / 2;       // 1600000
    const int* src = ei;
    const int* dst = ei + E;

    char* p = (char*)d_ws;
    ushort* h_buf = (ushort*)p; p += (size_t)n * D * sizeof(ushort);   // bf16 H'
    ushort* y_buf = (ushort*)p; p += (size_t)n * D * sizeof(ushort);   // bf16 y
    ushort* w1h   = (ushort*)p; p += (size_t)D * D * sizeof(ushort);
    ushort* w1l   = (ushort*)p; p += (size_t)D * D * sizeof(ushort);
    ushort* w2h   = (ushort*)p; p += (size_t)D * D * sizeof(ushort);
    ushort* w2l   = (ushort*)p; p += (size_t)D * D * sizeof(ushort);
    float* dinv   = (float*)p;  p += (size_t)n * sizeof(float);
    int*   degi   = (int*)p;    p += (size_t)n * sizeof(int);
    int*   row_ptr= (int*)p;    p += (size_t)(n + 1) * sizeof(int);
    int*   bsums  = (int*)p;    p += 1024 * sizeof(int);
    int*   rank   = (int*)p;    p += (size_t)E * sizeof(int);
    int*   col    = (int*)p;    p += (size_t)E * sizeof(int);

    int total = n + 1;
    int nb = (total + SCAN_CHUNK - 1) / SCAN_CHUNK;   // 98 for n=100000, fits 1024-thread scan

    k_init<<<(n + 255) / 256, 256, 0, stream>>>(degi, n);
    k_count_rank<<<(E + 255) / 256, 256, 0, stream>>>(dst, degi, rank, E);
    k_dinv<<<(n + 255) / 256, 256, 0, stream>>>(degi, dinv, n);
    k_scan_partial<<<nb, SCAN_BS, 0, stream>>>(degi, bsums, n, total);
    k_scan_sums<<<1, 1024, 0, stream>>>(bsums, nb);
    k_scan_write<<<nb, SCAN_BS, 0, stream>>>(degi, bsums, row_ptr, n, total);
    k_fill<<<(E + 255) / 256, 256, 0, stream>>>(src, dst, row_ptr, rank, col, E);

    k_prep_w<<<(D * D) / 256, 256, 0, stream>>>(W1, w1h, w1l);
    k_prep_w<<<(D * D) / 256, 256, 0, stream>>>(W2, w2h, w2l);

    int gemm_grid = (n + 127) / 128;
    int agg_grid  = (n + 3) / 4;

    // layer 1: h' = bf16(dinv * (x@W1)) ; y = bf16(relu(dinv * (A_sum h') + b1))
    k_gemm_mfma<true><<<gemm_grid, 256, 0, stream>>>(x, w1h, w1l, dinv, h_buf, n);
    k_agg<<<agg_grid, 256, 0, stream>>>(h_buf, row_ptr, col, dinv, b1, nullptr, y_buf, n, 1, 1);
    // layer 2: h2' = bf16(dinv * (y@W2)) ; out = dinv * (A_sum h2') + b2
    k_gemm_mfma<false><<<gemm_grid, 256, 0, stream>>>(y_buf, w2h, w2l, dinv, h_buf, n);
    k_agg<<<agg_grid, 256, 0, stream>>>(h_buf, row_ptr, col, dinv, b2, out, nullptr, n, 0, 0);
}

// Round 5
// 355.065 us; speedup vs baseline: 1.9802x; 1.0957x over previous
//
#include <hip/hip_runtime.h>

#define D 128

typedef unsigned int uint;
typedef unsigned short ushort;
typedef __attribute__((ext_vector_type(8))) short bf16x8_t;   // 8 bf16 = 4 VGPRs
typedef __attribute__((ext_vector_type(4))) float f32x4_t;    // MFMA accumulator

// ================= atomic-free CSR build: two-level bucket sort =================
// Level 1: partition edges by dst>>7 into nbuck buckets (782 for n=100000).
// Level 2: per-bucket (128 nodes, ~2K edges) LDS count/scan/rank -> CSR + dinv.
// All atomics are LDS-only; global writes are exact-offset scatters.
#define NB 128        // number of partition blocks
#define BSH 7         // bucket shift: 128 nodes per bucket
#define BMASK 127
#define MAXBUCK 1024  // supports n <= 131072

__global__ __launch_bounds__(256) void kp_hist(const int* __restrict__ dst,
                                               int* __restrict__ table,
                                               int E, int nbuck, int chunk) {
    __shared__ int h[MAXBUCK];
    int t = threadIdx.x, b = blockIdx.x;
    for (int i = t; i < nbuck; i += 256) h[i] = 0;
    __syncthreads();
    int s = b * chunk, e = min(E, s + chunk);
    for (int i = s + t; i < e; i += 256)
        atomicAdd(&h[dst[i] >> BSH], 1);
    __syncthreads();
    for (int i = t; i < nbuck; i += 256)
        table[i * NB + b] = h[i];               // bucket-major layout
}

// exclusive scan of each bucket's NB entries; bucket total -> btot
__global__ void kp_scan_table(int* __restrict__ table, int* __restrict__ btot) {
    __shared__ int s[NB];
    int t = threadIdx.x, b = blockIdx.x;
    int v = table[b * NB + t];
    s[t] = v; __syncthreads();
    for (int off = 1; off < NB; off <<= 1) {
        int x = (t >= off) ? s[t - off] : 0;
        __syncthreads();
        s[t] += x;
        __syncthreads();
    }
    table[b * NB + t] = s[t] - v;               // exclusive within bucket
    if (t == NB - 1) btot[b] = s[t];
}

// exclusive scan of bucket totals -> bucketBase; also finalize row_ptr[n]
__global__ void kp_scan_btot(const int* __restrict__ btot, int* __restrict__ bucketBase,
                             int* __restrict__ row_ptr, int nbuck, int E, int n) {
    __shared__ int s[1024];
    int t = threadIdx.x;
    int v = (t < nbuck) ? btot[t] : 0;
    s[t] = v; __syncthreads();
    for (int off = 1; off < 1024; off <<= 1) {
        int x = (t >= off) ? s[t - off] : 0;
        __syncthreads();
        s[t] += x;
        __syncthreads();
    }
    if (t < nbuck) bucketBase[t] = s[t] - v;
    if (t == 0) { bucketBase[nbuck] = E; row_ptr[n] = E; }
}

__global__ __launch_bounds__(256) void kp_scatter(const int* __restrict__ src,
                                                  const int* __restrict__ dst,
                                                  const int* __restrict__ table,
                                                  const int* __restrict__ bucketBase,
                                                  uint* __restrict__ sorted,
                                                  int E, int nbuck, int chunk) {
    __shared__ int off[MAXBUCK];
    int t = threadIdx.x, b = blockIdx.x;
    for (int i = t; i < nbuck; i += 256)
        off[i] = bucketBase[i] + table[i * NB + b];
    __syncthreads();
    int s = b * chunk, e = min(E, s + chunk);
    for (int i = s + t; i < e; i += 256) {
        int d = dst[i];
        int bk = d >> BSH;
        int slot = atomicAdd(&off[bk], 1);      // LDS atomic: unique slot in bucket region
        sorted[slot] = ((uint)src[i] << BSH) | (uint)(d & BMASK);
    }
}

// one block per bucket: local count/scan/rank -> row_ptr, col, dinv
__global__ __launch_bounds__(256) void kp_build(const uint* __restrict__ sorted,
                                                const int* __restrict__ bucketBase,
                                                int* __restrict__ row_ptr,
                                                int* __restrict__ col,
                                                float* __restrict__ dinv, int n) {
    __shared__ int cnt[128], loc[128], cnt2[128];
    int t = threadIdx.x, b = blockIdx.x;
    int base = bucketBase[b], end = bucketBase[b + 1];
    if (t < 128) { cnt[t] = 0; cnt2[t] = 0; }
    __syncthreads();
    for (int i = base + t; i < end; i += 256)
        atomicAdd(&cnt[sorted[i] & BMASK], 1);
    __syncthreads();
    int v = (t < 128) ? cnt[t] : 0;
    if (t < 128) loc[t] = v;
    __syncthreads();
    for (int off = 1; off < 128; off <<= 1) {   // inclusive scan of cnt in loc
        int x = (t >= off && t < 128) ? loc[t - off] : 0;
        __syncthreads();
        if (t < 128) loc[t] += x;
        __syncthreads();
    }
    int node = (b << BSH) + t;
    if (t < 128 && node < n) {
        row_ptr[node] = base + loc[t] - v;      // exclusive prefix
        dinv[node] = rsqrtf((float)(v + 1));    // deg = in-edges + self-loop
    }
    __syncthreads();
    for (int i = base + t; i < end; i += 256) {
        uint p = sorted[i];
        int low = p & BMASK;
        int r = atomicAdd(&cnt2[low], 1);
        col[base + (loc[low] - cnt[low]) + r] = (int)(p >> BSH);
    }
}

// ---------------- bf16 helpers ----------------
__device__ inline uint bf16rn(float f) {               // fp32 -> bf16 bits, round-nearest-even
    uint u = __float_as_uint(f);
    return (u + 0x7fffu + ((u >> 16) & 1u)) >> 16;
}

__device__ inline void accum_bf16x8(float* a, uint4 v) {
    a[0] += __uint_as_float(v.x << 16);
    a[1] += __uint_as_float(v.x & 0xffff0000u);
    a[2] += __uint_as_float(v.y << 16);
    a[3] += __uint_as_float(v.y & 0xffff0000u);
    a[4] += __uint_as_float(v.z << 16);
    a[5] += __uint_as_float(v.z & 0xffff0000u);
    a[6] += __uint_as_float(v.w << 16);
    a[7] += __uint_as_float(v.w & 0xffff0000u);
}

// ---------------- W prep: Wt_hi/Wt_lo[n][k] (bf16 split) from W[k][n] fp32 ----------------
__global__ void k_prep_w(const float* __restrict__ W, ushort* __restrict__ Wh,
                         ushort* __restrict__ Wl) {
    int i = blockIdx.x * blockDim.x + threadIdx.x;   // 16384
    int k = i >> 7, n = i & 127;
    float w = W[k * D + n];
    uint hb = bf16rn(w);
    float hf = __uint_as_float(hb << 16);
    uint lb = bf16rn(w - hf);
    Wh[n * D + k] = (ushort)hb;
    Wl[n * D + k] = (ushort)lb;
}

// ---------------- MFMA GEMM: Hb[M,128](bf16) = dinv[r] * (A[M,128] @ W[128,128]) ----------------
// A_FP32: A is fp32, split hi/lo -> 3 passes (AhWh + AlWh + AhWl), error ~2^-18.
// else:   A is bf16 (exact)      -> 2 passes (AhWh + AhWl).
// 128x128 block tile, BK=64, 4 waves x (64x64), LDS stride 72 bf16 (2-way = free).
template <bool A_FP32>
__global__ __launch_bounds__(256, 2) void k_gemm_mfma(const void* __restrict__ A,
                                                      const ushort* __restrict__ Wth,
                                                      const ushort* __restrict__ Wtl,
                                                      const float* __restrict__ dinv,
                                                      ushort* __restrict__ Yb, int M) {
    constexpr int STR = 72;                          // LDS row stride in bf16
    constexpr int TILE = 128 * STR;                  // 9216 ushorts per tile
    __shared__ ushort lds[A_FP32 ? 4 * TILE : 3 * TILE];
    ushort* Ah = lds;
    ushort* Wh = lds + TILE;
    ushort* Wl = lds + 2 * TILE;
    ushort* Al = A_FP32 ? (lds + 3 * TILE) : nullptr;

    int t = threadIdx.x;
    int lane = t & 63, wave = t >> 6;
    int quad = lane >> 4, l16 = lane & 15;
    int m_off = (wave & 1) * 64;                     // wave's 64x64 sub-tile
    int n_off = (wave >> 1) * 64;
    int block_row = blockIdx.x * 128;

    f32x4_t acc[4][4];
#pragma unroll
    for (int mt = 0; mt < 4; mt++)
#pragma unroll
        for (int nt = 0; nt < 4; nt++) acc[mt][nt] = (f32x4_t){0.f, 0.f, 0.f, 0.f};

    for (int kc = 0; kc < 128; kc += 64) {
        // ---- stage A ----
        if (A_FP32) {
            const float* Af = (const float*)A;
#pragma unroll
            for (int it = 0; it < 8; it++) {
                int s = t + it * 256;                // 2048 float4 slots
                int row = s >> 4, kl = (s & 15) * 4;
                int gr = block_row + row;
                float4 v = make_float4(0.f, 0.f, 0.f, 0.f);
                if (gr < M) v = *(const float4*)(Af + (size_t)gr * D + kc + kl);
                ushort4 h, l;
                uint hb, lb; float hf;
                hb = bf16rn(v.x); hf = __uint_as_float(hb << 16); lb = bf16rn(v.x - hf);
                h.x = (ushort)hb; l.x = (ushort)lb;
                hb = bf16rn(v.y); hf = __uint_as_float(hb << 16); lb = bf16rn(v.y - hf);
                h.y = (ushort)hb; l.y = (ushort)lb;
                hb = bf16rn(v.z); hf = __uint_as_float(hb << 16); lb = bf16rn(v.z - hf);
                h.z = (ushort)hb; l.z = (ushort)lb;
                hb = bf16rn(v.w); hf = __uint_as_float(hb << 16); lb = bf16rn(v.w - hf);
                h.w = (ushort)hb; l.w = (ushort)lb;
                *(ushort4*)&Ah[row * STR + kl] = h;
                *(ushort4*)&Al[row * STR + kl] = l;
            }
        } else {
            const ushort* Ab = (const ushort*)A;
#pragma unroll
            for (int it = 0; it < 4; it++) {
                int s = t + it * 256;                // 1024 16B slots
                int row = s >> 3, kl = (s & 7) * 8;
                int gr = block_row + row;
                uint4 v = make_uint4(0u, 0u, 0u, 0u);
                if (gr < M) v = *(const uint4*)(Ab + (size_t)gr * D + kc + kl);
                *(uint4*)&Ah[row * STR + kl] = v;
            }
        }
        // ---- stage W (pre-transposed bf16 hi/lo) ----
#pragma unroll
        for (int it = 0; it < 4; it++) {
            int s = t + it * 256;
            int nrow = s >> 3, kl = (s & 7) * 8;
            *(uint4*)&Wh[nrow * STR + kl] = *(const uint4*)(Wth + nrow * D + kc + kl);
            *(uint4*)&Wl[nrow * STR + kl] = *(const uint4*)(Wtl + nrow * D + kc + kl);
        }
        __syncthreads();

        // ---- MFMA over 2 k-steps of 32 ----
#pragma unroll
        for (int ks = 0; ks < 2; ks++) {
            int kf = ks * 32 + quad * 8;
            bf16x8_t ah[4], bh[4], bl[4];
#pragma unroll
            for (int mt = 0; mt < 4; mt++)
                ah[mt] = *(const bf16x8_t*)&Ah[(m_off + mt * 16 + l16) * STR + kf];
#pragma unroll
            for (int nt = 0; nt < 4; nt++) {
                bh[nt] = *(const bf16x8_t*)&Wh[(n_off + nt * 16 + l16) * STR + kf];
                bl[nt] = *(const bf16x8_t*)&Wl[(n_off + nt * 16 + l16) * STR + kf];
            }
            if (A_FP32) {
                bf16x8_t al[4];
#pragma unroll
                for (int mt = 0; mt < 4; mt++)
                    al[mt] = *(const bf16x8_t*)&Al[(m_off + mt * 16 + l16) * STR + kf];
#pragma unroll
                for (int mt = 0; mt < 4; mt++)
#pragma unroll
                    for (int nt = 0; nt < 4; nt++) {
                        acc[mt][nt] = __builtin_amdgcn_mfma_f32_16x16x32_bf16(ah[mt], bh[nt], acc[mt][nt], 0, 0, 0);
                        acc[mt][nt] = __builtin_amdgcn_mfma_f32_16x16x32_bf16(al[mt], bh[nt], acc[mt][nt], 0, 0, 0);
                        acc[mt][nt] = __builtin_amdgcn_mfma_f32_16x16x32_bf16(ah[mt], bl[nt], acc[mt][nt], 0, 0, 0);
                    }
            } else {
#pragma unroll
                for (int mt = 0; mt < 4; mt++)
#pragma unroll
                    for (int nt = 0; nt < 4; nt++) {
                        acc[mt][nt] = __builtin_amdgcn_mfma_f32_16x16x32_bf16(ah[mt], bh[nt], acc[mt][nt], 0, 0, 0);
                        acc[mt][nt] = __builtin_amdgcn_mfma_f32_16x16x32_bf16(ah[mt], bl[nt], acc[mt][nt], 0, 0, 0);
                    }
            }
        }
        __syncthreads();
    }

    // ---- epilogue: C layout col=lane&15, row=quad*4+reg; scale by dinv, pack bf16 ----
#pragma unroll
    for (int mt = 0; mt < 4; mt++) {
#pragma unroll
        for (int reg = 0; reg < 4; reg++) {
            int gr = block_row + m_off + mt * 16 + quad * 4 + reg;
            if (gr < M) {
                float di = dinv[gr];
#pragma unroll
                for (int nt = 0; nt < 4; nt++) {
                    int colg = n_off + nt * 16 + l16;
                    Yb[(size_t)gr * D + colg] = (ushort)bf16rn(di * acc[mt][nt][reg]);
                }
            }
        }
    }
}

// ---------------- pull aggregation on pre-scaled bf16 H':
//   Y[d] = dinv[d] * (H'[d] + sum_{s in row d} H'[s]) + b   (optional relu; optional bf16 out)
// One wave per node. Quarter-wave (16 lanes x 16B = 256B) per edge row -> 4 chains;
// 2x unroll per chain -> 8 independent row-gathers in flight per wave.
__global__ __launch_bounds__(256) void k_agg(const ushort* __restrict__ Hb,
                                             const int* __restrict__ row_ptr,
                                             const int* __restrict__ col,
                                             const float* __restrict__ dinv,
                                             const float* __restrict__ bias,
                                             float* __restrict__ Yf, ushort* __restrict__ Yb,
                                             int n, int do_relu, int out_bf16) {
    int node = blockIdx.x * 4 + (threadIdx.x >> 6);
    int lane = threadIdx.x & 63;
    int chain = lane >> 4;       // 0..3: which edge chain
    int l16   = lane & 15;       // 16B slot: bf16 cols 8*l16 .. 8*l16+7
    if (node >= n) return;

    int start = row_ptr[node];
    int end   = row_ptr[node + 1];

    float a0[8], a1[8];
#pragma unroll
    for (int k = 0; k < 8; k++) { a0[k] = 0.f; a1[k] = 0.f; }

    if (chain == 0) {            // self-loop row in chain 0
        uint4 v = ((const uint4*)(Hb + (size_t)node * D))[l16];
        accum_bf16x8(a0, v);
    }

    int e = start + chain;
    for (; e + 4 < end; e += 8) {
        int s0 = col[e];
        int s1 = col[e + 4];
        uint4 v0 = ((const uint4*)(Hb + (size_t)s0 * D))[l16];
        uint4 v1 = ((const uint4*)(Hb + (size_t)s1 * D))[l16];
        accum_bf16x8(a0, v0);
        accum_bf16x8(a1, v1);
    }
    if (e < end) {               // at most one tail element per chain
        int s0 = col[e];
        uint4 v0 = ((const uint4*)(Hb + (size_t)s0 * D))[l16];
        accum_bf16x8(a0, v0);
    }

    float acc[8];
#pragma unroll
    for (int k = 0; k < 8; k++) {
        float v = a0[k] + a1[k];
        v += __shfl_xor(v, 16, 64);   // combine chains 0<->1, 2<->3
        v += __shfl_xor(v, 32, 64);   // combine pairs
        acc[k] = v;
    }

    if (chain == 0) {            // lanes 0..15 hold the full row (cols 8*l16..8*l16+7)
        float di = dinv[node];
        const float4* bp = (const float4*)bias + l16 * 2;
        float4 b0 = bp[0], b1 = bp[1];
        float o[8];
        o[0] = fmaf(di, acc[0], b0.x); o[1] = fmaf(di, acc[1], b0.y);
        o[2] = fmaf(di, acc[2], b0.z); o[3] = fmaf(di, acc[3], b0.w);
        o[4] = fmaf(di, acc[4], b1.x); o[5] = fmaf(di, acc[5], b1.y);
        o[6] = fmaf(di, acc[6], b1.z); o[7] = fmaf(di, acc[7], b1.w);
        if (do_relu) {
#pragma unroll
            for (int k = 0; k < 8; k++) o[k] = fmaxf(o[k], 0.f);
        }
        if (out_bf16) {
            uint4 pk;
            pk.x = bf16rn(o[0]) | (bf16rn(o[1]) << 16);
            pk.y = bf16rn(o[2]) | (bf16rn(o[3]) << 16);
            pk.z = bf16rn(o[4]) | (bf16rn(o[5]) << 16);
            pk.w = bf16rn(o[6]) | (bf16rn(o[7]) << 16);
            ((uint4*)(Yb + (size_t)node * D))[l16] = pk;
        } else {
            float4* yp = (float4*)(Yf + (size_t)node * D) + l16 * 2;
            yp[0] = make_float4(o[0], o[1], o[2], o[3]);
            yp[1] = make_float4(o[4], o[5], o[6], o[7]);
        }
    }
}

// ---------------- host ----------------
extern "C" void kernel_launch(void* const* d_in, const int* in_sizes, int n_in,
                              void* d_out, int out_size, void* d_ws, size_t ws_size,
                              hipStream_t stream) {
    const float* x  = (const float*)d_in[0];
    const int*   ei = (const int*)d_in[1];
    const float* W1 = (const float*)d_in[2];
    const float* b1 = (const float*)d_in[3];
    const float* W2 = (const float*)d_in[4];
    const float* b2 = (const float*)d_in[5];
    float* out = (float*)d_out;

    int n = in_sizes[0] / D;       // 100000
    int E = in_sizes[1] / 2;       // 1600000
    const int* src = ei;
    const int* dst = ei + E;

    char* p = (char*)d_ws;
    ushort* h_buf = (ushort*)p; p += (size_t)n * D * sizeof(ushort);   // bf16 H'
    ushort* y_buf = (ushort*)p; p += (size_t)n * D * sizeof(ushort);   // bf16 y
    ushort* w1h   = (ushort*)p; p += (size_t)D * D * sizeof(ushort);
    ushort* w1l   = (ushort*)p; p += (size_t)D * D * sizeof(ushort);
    ushort* w2h   = (ushort*)p; p += (size_t)D * D * sizeof(ushort);
    ushort* w2l   = (ushort*)p; p += (size_t)D * D * sizeof(ushort);
    float* dinv   = (float*)p;  p += (size_t)n * sizeof(float);
    int*   row_ptr= (int*)p;    p += (size_t)(n + 1) * sizeof(int);
    int*   table  = (int*)p;    p += (size_t)MAXBUCK * NB * sizeof(int);
    int*   btot   = (int*)p;    p += (size_t)MAXBUCK * sizeof(int);
    int*   bbase  = (int*)p;    p += (size_t)(MAXBUCK + 1) * sizeof(int);
    uint*  sorted = (uint*)p;   p += (size_t)E * sizeof(uint);
    int*   col    = (int*)p;    p += (size_t)E * sizeof(int);

    int nbuck = (n + BMASK) >> BSH;                  // 782
    int chunk = (E + NB - 1) / NB;                   // 12500

    kp_hist<<<NB, 256, 0, stream>>>(dst, table, E, nbuck, chunk);
    kp_scan_table<<<nbuck, NB, 0, stream>>>(table, btot);
    kp_scan_btot<<<1, 1024, 0, stream>>>(btot, bbase, row_ptr, nbuck, E, n);
    kp_scatter<<<NB, 256, 0, stream>>>(src, dst, table, bbase, sorted, E, nbuck, chunk);
    kp_build<<<nbuck, 256, 0, stream>>>(sorted, bbase, row_ptr, col, dinv, n);

    k_prep_w<<<(D * D) / 256, 256, 0, stream>>>(W1, w1h, w1l);
    k_prep_w<<<(D * D) / 256, 256, 0, stream>>>(W2, w2h, w2l);

    int gemm_grid = (n + 127) / 128;
    int agg_grid  = (n + 3) / 4;

    // layer 1: h' = bf16(dinv * (x@W1)) ; y = bf16(relu(dinv * (A_sum h') + b1))
    k_gemm_mfma<true><<<gemm_grid, 256, 0, stream>>>(x, w1h, w1l, dinv, h_buf, n);
    k_agg<<<agg_grid, 256, 0, stream>>>(h_buf, row_ptr, col, dinv, b1, nullptr, y_buf, n, 1, 1);
    // layer 2: h2' = bf16(dinv * (y@W2)) ; out = dinv * (A_sum h2') + b2
    k_gemm_mfma<false><<<gemm_grid, 256, 0, stream>>>(y_buf, w2h, w2l, dinv, h_buf, n);
    k_agg<<<agg_grid, 256, 0, stream>>>(h_buf, row_ptr, col, dinv, b2, out, nullptr, n, 0, 0);
}